// Round 1
// baseline (531.869 us; speedup 1.0000x reference)
//
#include <hip/hip_runtime.h>
#include <math.h>

#define NBINS 64
#define RADIUS 3
#define WIN (2*RADIUS+1)
#define HIST_ELEMS (NBINS*NBINS)

// ---- monotone float<->uint keys (work for any sign) ----
static __device__ __forceinline__ unsigned f2key(float f) {
    unsigned u = __float_as_uint(f);
    return (u & 0x80000000u) ? ~u : (u | 0x80000000u);
}
static __device__ __forceinline__ float key2f(unsigned u) {
    return (u & 0x80000000u) ? __uint_as_float(u & 0x7fffffffu) : __uint_as_float(~u);
}

// ws layout: [0..7] uint minmax keys  (idx = n*4 + tensor*2 + {0:min,1:max})
//            at byte offset 256: float hist[2][64*64]
__global__ void init_ws_kernel(unsigned* __restrict__ mm, float* __restrict__ hist) {
    int i = blockIdx.x * blockDim.x + threadIdx.x;
    if (i < 8) mm[i] = (i & 1) ? 0u : 0xFFFFFFFFu;  // min-slot: max key, max-slot: 0
    for (int j = i; j < 2 * HIST_ELEMS; j += gridDim.x * blockDim.x) hist[j] = 0.0f;
}

__global__ __launch_bounds__(256) void minmax_kernel(const float* __restrict__ tar,
                                                     const float* __restrict__ src,
                                                     unsigned* __restrict__ mm, int P) {
    const int n = blockIdx.y;
    const int t = blockIdx.z;
    const float* x = (t == 0 ? tar : src) + (size_t)n * P;
    float lmin = INFINITY, lmax = -INFINITY;
    for (int i = blockIdx.x * blockDim.x + threadIdx.x; i < P; i += gridDim.x * blockDim.x) {
        float v = x[i];
        lmin = fminf(lmin, v);
        lmax = fmaxf(lmax, v);
    }
    for (int off = 32; off > 0; off >>= 1) {
        lmin = fminf(lmin, __shfl_down(lmin, off, 64));
        lmax = fmaxf(lmax, __shfl_down(lmax, off, 64));
    }
    __shared__ float smin[4], smax[4];
    const int lane = threadIdx.x & 63, wave = threadIdx.x >> 6;
    if (lane == 0) { smin[wave] = lmin; smax[wave] = lmax; }
    __syncthreads();
    if (threadIdx.x == 0) {
        float m = fminf(fminf(smin[0], smin[1]), fminf(smin[2], smin[3]));
        float M = fmaxf(fmaxf(smax[0], smax[1]), fmaxf(smax[2], smax[3]));
        atomicMin(&mm[(n * 2 + t) * 2 + 0], f2key(m));
        atomicMax(&mm[(n * 2 + t) * 2 + 1], f2key(M));
    }
}

__global__ __launch_bounds__(256) void hist_kernel(const float* __restrict__ tar,
                                                   const float* __restrict__ src,
                                                   const unsigned* __restrict__ mm,
                                                   float* __restrict__ ghist, int P) {
    const int n = blockIdx.y;
    __shared__ float lh[HIST_ELEMS];
    for (int i = threadIdx.x; i < HIST_ELEMS; i += blockDim.x) lh[i] = 0.0f;
    __syncthreads();

    const float tmin = key2f(mm[n * 4 + 0]);
    const float tmax = key2f(mm[n * 4 + 1]);
    const float smin = key2f(mm[n * 4 + 2]);
    const float smax = key2f(mm[n * 4 + 3]);
    const float tscale = 63.0f / (tmax - tmin + 1e-10f);
    const float sscale = 63.0f / (smax - smin + 1e-10f);
    // exponent: -d^2/(2*sigma^2), d=(u-b)/63, sigma=1/128 -> K = 8192/63^2
    const float K = 8192.0f / (63.0f * 63.0f);
    const float* t = tar + (size_t)n * P;
    const float* s = src + (size_t)n * P;

    for (int i = blockIdx.x * blockDim.x + threadIdx.x; i < P; i += gridDim.x * blockDim.x) {
        float ut = (t[i] - tmin) * tscale;   // position in bin units, [0,63]
        float us = (s[i] - smin) * sscale;
        int ct = __float2int_rn(ut);
        int cs = __float2int_rn(us);
        int bt0 = max(0, ct - RADIUS), bt1 = min(NBINS - 1, ct + RADIUS);
        int bs0 = max(0, cs - RADIUS), bs1 = min(NBINS - 1, cs + RADIUS);
        int nsj = bs1 - bs0;
        float wsv[WIN];
        for (int j = 0; j <= nsj; ++j) {
            float d = us - (float)(bs0 + j);
            wsv[j] = __expf(-K * d * d);
        }
        for (int bt = bt0; bt <= bt1; ++bt) {
            float d = ut - (float)bt;
            float wt = __expf(-K * d * d);
            float* row = &lh[bt * NBINS + bs0];
            for (int j = 0; j <= nsj; ++j) {
                unsafeAtomicAdd(&row[j], wt * wsv[j]);
            }
        }
    }
    __syncthreads();
    float* gh = ghist + (size_t)n * HIST_ELEMS;
    for (int i = threadIdx.x; i < HIST_ELEMS; i += blockDim.x) {
        float v = lh[i];
        if (v != 0.0f) unsafeAtomicAdd(&gh[i], v);
    }
}

static __device__ __forceinline__ float block_reduce_sum(float v, float* buf) {
    for (int off = 32; off > 0; off >>= 1) v += __shfl_down(v, off, 64);
    const int lane = threadIdx.x & 63, wave = threadIdx.x >> 6;
    __syncthreads();  // protect buf from any previous use
    if (lane == 0) buf[wave] = v;
    __syncthreads();
    return buf[0] + buf[1] + buf[2] + buf[3];
}

__global__ __launch_bounds__(256) void finalize_kernel(const float* __restrict__ ghist,
                                                       float* __restrict__ out) {
    __shared__ float buf[4];
    __shared__ float marg[2 * NBINS];
    const int tid = threadIdx.x;
    float acc = 0.0f;
    for (int n = 0; n < 2; ++n) {
        const float* h = ghist + n * HIST_ELEMS;
        float tsum = 0.0f;
        for (int i = tid; i < HIST_ELEMS; i += 256) tsum += h[i];
        float total = block_reduce_sum(tsum, buf);
        float inv = 1.0f / total;

        float ej = 0.0f;
        for (int i = tid; i < HIST_ELEMS; i += 256) {
            float p = h[i] * inv;
            ej += p * logf(p + 1e-10f);
        }
        float entj = -block_reduce_sum(ej, buf);

        if (tid < NBINS) {
            float pt = 0.0f, ps = 0.0f;
            for (int c = 0; c < NBINS; ++c) {
                pt += h[tid * NBINS + c];
                ps += h[c * NBINS + tid];
            }
            pt *= inv; ps *= inv;
            marg[tid] = pt * logf(pt + 1e-10f);
            marg[NBINS + tid] = ps * logf(ps + 1e-10f);
        }
        __syncthreads();
        float m = (tid < 2 * NBINS) ? marg[tid] : 0.0f;
        float ent_t_plus_s = -block_reduce_sum(m, buf);

        acc += ent_t_plus_s / entj;
        __syncthreads();
    }
    if (tid == 0) out[0] = -0.5f * acc;  // mean over N=2, negated
}

extern "C" void kernel_launch(void* const* d_in, const int* in_sizes, int n_in,
                              void* d_out, int out_size, void* d_ws, size_t ws_size,
                              hipStream_t stream) {
    const float* tar = (const float*)d_in[0];
    const float* src = (const float*)d_in[1];
    const int N = 2;
    const int P = in_sizes[0] / N;  // 96*96*96 = 884736

    unsigned* mm = (unsigned*)d_ws;
    float* hist = (float*)((char*)d_ws + 256);
    float* out = (float*)d_out;

    init_ws_kernel<<<33, 256, 0, stream>>>(mm, hist);
    minmax_kernel<<<dim3(64, N, 2), 256, 0, stream>>>(tar, src, mm, P);
    hist_kernel<<<dim3(256, N, 1), 256, 0, stream>>>(tar, src, mm, hist, P);
    finalize_kernel<<<1, 256, 0, stream>>>(hist, out);
}